// Round 6
// baseline (174.338 us; speedup 1.0000x reference)
//
#include <hip/hip_runtime.h>
#include <math.h>

#define BB 32
#define CCH 224
#define TTT 2048
#define BT (BB*TTT)        // 65536
#define TPB 64             // t per kf tile
#define NT  (TTT/TPB)      // 32 tiles
#define CG  28             // channels per kf block
#define NCG (CCH/CG)       // 8  -> 256 blocks = 1 block/CU
#define IROW 29            // f64 per Is row (28 + 1 pad)

// flag indices (generation counters, monotone, no reset)
#define PF(s,h) ((s)*2+(h))     // conv wave h wrote Is slot s
#define CF(s)   (4+(s))         // scan consumed Is slot s
#define SF(s)   (6+(s))         // scan wrote bits slot s
#define OF(s,h) (8+(s)*2+(h))   // conv wave h consumed bits slot s

// ---------------------------------------------------------------------------
// kw: per (b,t): f64 dot over C -> w -> 7 symmetric Gaussian taps (f64, SoA).
// grid (8 t-chunks, 32 b) x 256. Phase1: thread (q,m) = t-quad x channel-56-group,
// float4 loads (bit-identical per-partial order to prior rounds).
// Phase2: one thread per t does the recurrence tail (all 256 threads busy).
// ---------------------------------------------------------------------------
__global__ __launch_bounds__(256) void kw(
    const float* __restrict__ x, const float* __restrict__ lw,
    double* __restrict__ kernG)
{
    __shared__ double sd[4][256];
    __shared__ float  lws[CCH];
    const int b   = blockIdx.y;
    const int t0  = blockIdx.x * 256;
    const int tid = threadIdx.x;

    if (tid < CCH) lws[tid] = lw[tid];
    __syncthreads();

    {   // phase 1
        const int q = tid & 63, m = tid >> 6;
        const float* xb = x + (((size_t)(b * CCH + 56 * m)) << 11) + t0 + 4 * q;
        double a0 = 0, a1 = 0, a2 = 0, a3 = 0;
        #pragma unroll 8
        for (int i = 0; i < 56; ++i) {
            float4 v = *(const float4*)(xb + ((size_t)i << 11));
            double wv = (double)lws[56 * m + i];
            a0 += (double)v.x * wv;
            a1 += (double)v.y * wv;
            a2 += (double)v.z * wv;
            a3 += (double)v.w * wv;
        }
        sd[m][4 * q + 0] = a0; sd[m][4 * q + 1] = a1;
        sd[m][4 * q + 2] = a2; sd[m][4 * q + 3] = a3;
    }
    __syncthreads();

    {   // phase 2: tail per t
        double s2 = (sd[0][tid] + sd[1][tid]) + (sd[2][tid] + sd[3][tid]);

        double w = 5.2 + s2 * 9.6;
        w = fmin(fmax(w, 0.4), 10.0);
        double iw2 = 1.0 / (w * w);

        const double s = 120.0 / 129.0;
        double G  = exp(-0.125 * s * s * iw2);
        double G2 = G * G, G4 = G2 * G2, G8 = G4 * G4;
        double term = G, cmul = G8, norm = G;
        for (int u = 1; u <= 64; ++u) { term *= cmul; cmul *= G8; norm += term; }
        norm *= 2.0;

        double P = exp(-0.5 * iw2), P2 = P * P;
        double a = 1.0, bm = P, inv = 1.0 / norm;
        double* kr = kernG + (size_t)b * TTT + t0 + tid;   // SoA [d][b*T+t]
        kr[0] = inv;
        #pragma unroll
        for (int d = 1; d <= 6; ++d) {
            a *= bm; bm *= P2;
            kr[(size_t)d * BT] = a * inv;
        }
    }
}

// ---------------------------------------------------------------------------
// kf: barrier-free fused conv + LIF scan + spike output.
// grid (8, 32) x 192: wave0 = scan (28 chains); waves 1,2 = conv halves
// (14 channels each), x/kern loaded DIRECTLY to registers (coalesced along t).
// Is ring depth 2 in LDS; bits ring depth 2; LDS generation flags (acq/rel).
// ---------------------------------------------------------------------------
__global__ __launch_bounds__(192) void kf(
    const float* __restrict__ x, const double* __restrict__ kernG,
    float* __restrict__ out)
{
    __shared__ double Is[2][TPB][IROW];                 // 29,696 B
    __shared__ unsigned long long bitsb[2][CG];         //    448 B
    __shared__ int fl[16];

    const int b    = blockIdx.y;
    const int c0   = blockIdx.x * CG;
    const int tid  = threadIdx.x;
    const int wid  = tid >> 6;
    const int lane = tid & 63;

    if (tid < 16) fl[tid] = 0;
    __syncthreads();

    const float*  xbase = x + (((size_t)(b * CCH)) << 11);
    const double* kbase = kernG + (size_t)b * TTT;
    float* obase = out + (((size_t)(b * CCH + c0)) << 11);

    if (wid >= 1) {
        // ================= conv / stage / out-write wave =================
        const int h  = wid - 1;
        const int cb = 14 * h;                // channel base within group
        const int crow0 = c0 + cb - 6;        // first x row needed
        float  xc[26], xn[26];
        double kc[7],  kn[7];

        #pragma unroll
        for (int i = 0; i < 26; ++i) {
            int cr = crow0 + i;
            xc[i] = (cr >= 0 && cr < CCH) ? xbase[((size_t)cr << 11) + lane] : 0.0f;
        }
        #pragma unroll
        for (int d = 0; d < 7; ++d) kc[d] = kbase[(size_t)d * BT + lane];

        #pragma unroll 1
        for (int k = 0; k <= NT + 1; ++k) {
            // 1) issue next tile's loads (latency hidden by one full iteration)
            if (k + 1 <= NT - 1) {
                const int gt = (k + 1) * TPB + lane;
                #pragma unroll
                for (int i = 0; i < 26; ++i) {
                    int cr = crow0 + i;
                    xn[i] = (cr >= 0 && cr < CCH) ? xbase[((size_t)cr << 11) + gt] : 0.0f;
                }
                #pragma unroll
                for (int d = 0; d < 7; ++d) kn[d] = kbase[(size_t)d * BT + gt];
            }
            // 2) conv tile k -> Is slot k&1
            if (k <= NT - 1) {
                const int s = k & 1;
                while (__hip_atomic_load(&fl[CF(s)], __ATOMIC_ACQUIRE,
                                         __HIP_MEMORY_SCOPE_WORKGROUP) < k - 1)
                    __builtin_amdgcn_s_sleep(1);
                #pragma unroll
                for (int c = 0; c < 14; ++c) {
                    double acc = 0.0;
                    #pragma unroll
                    for (int kk = 0; kk < 13; ++kk) {
                        int d = kk < 6 ? 6 - kk : kk - 6;
                        acc = fma((double)xc[c + kk], kc[d], acc);
                    }
                    double xvv = (double)xc[c + 6];
                    double dd  = xvv - acc;
                    Is[s][lane][cb + c] = xvv - (dd > 0.0 ? dd : 0.0);
                }
                if (lane == 0)
                    __hip_atomic_store(&fl[PF(s, h)], k + 1, __ATOMIC_RELEASE,
                                       __HIP_MEMORY_SCOPE_WORKGROUP);
            }
            // 3) out-write tile j = k-2: THIS wave's 14 channels only
            const int j = k - 2;
            if (j >= 0) {
                const int s2 = j & 1;
                while (__hip_atomic_load(&fl[SF(s2)], __ATOMIC_ACQUIRE,
                                         __HIP_MEMORY_SCOPE_WORKGROUP) < j + 1)
                    __builtin_amdgcn_s_sleep(1);
                // read all needed bits into registers first
                unsigned long long bb[4];
                #pragma unroll
                for (int i = 0; i < 4; ++i) {
                    int e = lane + (i << 6);              // 0..255
                    int cl = (e < 224) ? (e >> 4) : 13;   // clamp (unused lanes)
                    bb[i] = bitsb[s2][cb + cl];
                }
                if (lane == 0)
                    __hip_atomic_store(&fl[OF(s2, h)], j + 1, __ATOMIC_RELEASE,
                                       __HIP_MEMORY_SCOPE_WORKGROUP);
                #pragma unroll
                for (int i = 0; i < 4; ++i) {
                    int e = lane + (i << 6);
                    if (e < 224) {                        // 14 ch x 16 float4
                        int cl = e >> 4, qq = e & 15;
                        unsigned long long bv = bb[i] >> (4 * qq);
                        float4 v;
                        v.x = (bv & 1ull) ? 1.0f : 0.0f;
                        v.y = (bv & 2ull) ? 1.0f : 0.0f;
                        v.z = (bv & 4ull) ? 1.0f : 0.0f;
                        v.w = (bv & 8ull) ? 1.0f : 0.0f;
                        *(float4*)(obase + ((size_t)(cb + cl) << 11) + j * TPB + 4 * qq) = v;
                    }
                }
            }
            // 4) rotate register ring
            if (k + 1 <= NT - 1) {
                #pragma unroll
                for (int i = 0; i < 26; ++i) xc[i] = xn[i];
                #pragma unroll
                for (int d = 0; d < 7; ++d) kc[d] = kn[d];
            }
        }
    } else {
        // ========================== scan wave ===========================
        const int c    = lane;
        const int cidx = (c < CG) ? c : 0;    // keep inactive lanes in-bounds
        double mem = 0.0;
        bool   r   = false;

        #pragma unroll 1
        for (int k = 0; k < NT; ++k) {
            const int s = k & 1;
            while (__hip_atomic_load(&fl[PF(s, 0)], __ATOMIC_ACQUIRE,
                                     __HIP_MEMORY_SCOPE_WORKGROUP) < k + 1 ||
                   __hip_atomic_load(&fl[PF(s, 1)], __ATOMIC_ACQUIRE,
                                     __HIP_MEMORY_SCOPE_WORKGROUP) < k + 1)
                __builtin_amdgcn_s_sleep(1);

            unsigned long long bits = 0ull;
            {
                double va[8], vb[8];
                #pragma unroll
                for (int j2 = 0; j2 < 8; ++j2) va[j2] = Is[s][j2][cidx];
                #pragma unroll
                for (int g = 0; g < 64; g += 16) {
                    #pragma unroll
                    for (int j2 = 0; j2 < 8; ++j2) vb[j2] = Is[s][g + 8 + j2][cidx];
                    #pragma unroll
                    for (int j2 = 0; j2 < 8; ++j2) {
                        double a2 = va[j2];
                        double cm = a2 - 1.0;
                        double m1 = fma(0.95, mem, a2);
                        double m2 = fma(0.95, mem, cm);
                        mem = r ? m2 : m1;
                        r = mem > 1.0;
                        bits |= (unsigned long long)(r ? 1 : 0) << (g + j2);
                    }
                    if (g + 16 < 64) {
                        #pragma unroll
                        for (int j2 = 0; j2 < 8; ++j2) va[j2] = Is[s][g + 16 + j2][cidx];
                    }
                    #pragma unroll
                    for (int j2 = 0; j2 < 8; ++j2) {
                        double a2 = vb[j2];
                        double cm = a2 - 1.0;
                        double m1 = fma(0.95, mem, a2);
                        double m2 = fma(0.95, mem, cm);
                        mem = r ? m2 : m1;
                        r = mem > 1.0;
                        bits |= (unsigned long long)(r ? 1 : 0) << (g + 8 + j2);
                    }
                }
            }
            if (lane == 0)
                __hip_atomic_store(&fl[CF(s)], k + 1, __ATOMIC_RELEASE,
                                   __HIP_MEMORY_SCOPE_WORKGROUP);

            const int s2 = k & 1;
            while (__hip_atomic_load(&fl[OF(s2, 0)], __ATOMIC_ACQUIRE,
                                     __HIP_MEMORY_SCOPE_WORKGROUP) < k - 1 ||
                   __hip_atomic_load(&fl[OF(s2, 1)], __ATOMIC_ACQUIRE,
                                     __HIP_MEMORY_SCOPE_WORKGROUP) < k - 1)
                __builtin_amdgcn_s_sleep(1);
            if (c < CG) bitsb[s2][c] = bits;
            if (lane == 0)
                __hip_atomic_store(&fl[SF(s2)], k + 1, __ATOMIC_RELEASE,
                                   __HIP_MEMORY_SCOPE_WORKGROUP);
        }
    }
}

// ---------------------------------------------------------------------------
extern "C" void kernel_launch(void* const* d_in, const int* in_sizes, int n_in,
                              void* d_out, int out_size, void* d_ws, size_t ws_size,
                              hipStream_t stream)
{
    const float* x  = (const float*)d_in[0];   // (32,1,224,2048) f32
    const float* lw = (const float*)d_in[1];   // (1,224) f32
    float* out = (float*)d_out;                // (32,1,224,2048) f32

    double* kernG = (double*)d_ws;             // SoA 7 * 65536 * 8 = 3,670,016 B

    kw<<<dim3(TTT / 256, BB), 256, 0, stream>>>(x, lw, kernG);
    kf<<<dim3(NCG, BB), 192, 0, stream>>>(x, kernG, out);
}

// Round 7
// 157.525 us; speedup vs baseline: 1.1067x; 1.1067x over previous
//
#include <hip/hip_runtime.h>
#include <math.h>

#define BB 32
#define CCH 224
#define TTT 2048
#define BT (BB*TTT)        // 65536
#define TPB 64             // t per kf tile
#define NT  (TTT/TPB)      // 32 tiles
#define CG  28             // channels per kf block
#define NCG (CCH/CG)       // 8  -> 256 blocks = 1 block/CU
#define IROW 29            // f64 per Is row (28 + 1 pad)
#define RD 4               // ring depth

// ---------------------------------------------------------------------------
// kw: per (b,t): f64 dot over C -> w -> 7 symmetric Gaussian taps (f64, SoA).
// grid (32 t-tiles, 32 b) x 256 = 1024 blocks (4/CU). thread = (t-quad q, 14-ch
// group g): 14 independent float4 loads in flight -> BW-bound, not latency.
// ---------------------------------------------------------------------------
__global__ __launch_bounds__(256) void kw(
    const float* __restrict__ x, const float* __restrict__ lw,
    double* __restrict__ kernG)
{
    __shared__ double sd[16][64];
    __shared__ float  lws[CCH];
    const int b   = blockIdx.y;
    const int t0  = blockIdx.x * 64;
    const int tid = threadIdx.x;

    if (tid < CCH) lws[tid] = lw[tid];
    __syncthreads();

    {   // phase 1: partial dots, 16 groups x 14 channels
        const int q = tid & 15, g = tid >> 4;
        const float* xb = x + (((size_t)(b * CCH + g * 14)) << 11) + t0 + 4 * q;
        double a0 = 0, a1 = 0, a2 = 0, a3 = 0;
        #pragma unroll
        for (int i = 0; i < 14; ++i) {
            float4 v = *(const float4*)(xb + ((size_t)i << 11));
            double wv = (double)lws[g * 14 + i];
            a0 += (double)v.x * wv;
            a1 += (double)v.y * wv;
            a2 += (double)v.z * wv;
            a3 += (double)v.w * wv;
        }
        sd[g][4 * q + 0] = a0; sd[g][4 * q + 1] = a1;
        sd[g][4 * q + 2] = a2; sd[g][4 * q + 3] = a3;
    }
    __syncthreads();

    if (tid < 64) {   // phase 2: tail per t
        const int t = tid;
        double s2 = 0.0;
        #pragma unroll
        for (int g = 0; g < 16; ++g) s2 += sd[g][t];

        double w = 5.2 + s2 * 9.6;
        w = fmin(fmax(w, 0.4), 10.0);
        double iw2 = 1.0 / (w * w);

        const double s = 120.0 / 129.0;
        double G  = exp(-0.125 * s * s * iw2);
        double G2 = G * G, G4 = G2 * G2, G8 = G4 * G4;
        double term = G, cmul = G8, norm = G;
        for (int u = 1; u <= 64; ++u) { term *= cmul; cmul *= G8; norm += term; }
        norm *= 2.0;

        double P = exp(-0.5 * iw2), P2 = P * P;
        double a = 1.0, bm = P, inv = 1.0 / norm;
        double* kr = kernG + (size_t)b * TTT + t0 + t;   // SoA [d][b*T+t]
        kr[0] = inv;
        #pragma unroll
        for (int d = 1; d <= 6; ++d) {
            a *= bm; bm *= P2;
            kr[(size_t)d * BT] = a * inv;
        }
    }
}

// ---------------------------------------------------------------------------
// kf: barrier-free fused conv + LIF scan + spike output, 4 specialized waves.
// wave0 = scan only; waves 1,2 = conv halves (14 ch each, regs-only staging);
// wave3 = out-writer. Is ring depth 4; bits ring depth 4; LDS gen-flags.
// ---------------------------------------------------------------------------
#define PF(h,s) ((h)*RD+(s))    // conv wave h wrote Is slot s      (fl[0..7])
#define CF(s)   (8+(s))         // scan consumed Is slot s          (fl[8..11])
#define SF(s)   (12+(s))        // scan wrote bits slot s           (fl[12..15])
#define OW(s)   (16+(s))        // out-writer consumed bits slot s  (fl[16..19])

__global__ __launch_bounds__(256) void kf(
    const float* __restrict__ x, const double* __restrict__ kernG,
    float* __restrict__ out)
{
    __shared__ double Is[RD][TPB][IROW];                // 59,392 B
    __shared__ unsigned long long bitsb[RD][CG];        //    896 B
    __shared__ int fl[32];

    const int b    = blockIdx.y;
    const int c0   = blockIdx.x * CG;
    const int tid  = threadIdx.x;
    const int wid  = tid >> 6;
    const int lane = tid & 63;

    if (tid < 32) fl[tid] = 0;
    __syncthreads();

    const float*  xbase = x + (((size_t)(b * CCH)) << 11);
    const double* kbase = kernG + (size_t)b * TTT;
    float* obase = out + (((size_t)(b * CCH + c0)) << 11);

    if (wid == 1 || wid == 2) {
        // ======================= conv wave (14 ch) =======================
        const int h  = wid - 1;
        const int cb = 14 * h;
        const int crow0 = c0 + cb - 6;
        float  xc[26], xn[26];
        double kc[7],  kn[7];

        #pragma unroll
        for (int i = 0; i < 26; ++i) {
            int cr = crow0 + i;
            xc[i] = (cr >= 0 && cr < CCH) ? xbase[((size_t)cr << 11) + lane] : 0.0f;
        }
        #pragma unroll
        for (int d = 0; d < 7; ++d) kc[d] = kbase[(size_t)d * BT + lane];

        #pragma unroll 1
        for (int k = 0; k < NT; ++k) {
            // issue next tile's loads (consumed next iteration)
            if (k + 1 < NT) {
                const int gt = (k + 1) * TPB + lane;
                #pragma unroll
                for (int i = 0; i < 26; ++i) {
                    int cr = crow0 + i;
                    xn[i] = (cr >= 0 && cr < CCH) ? xbase[((size_t)cr << 11) + gt] : 0.0f;
                }
                #pragma unroll
                for (int d = 0; d < 7; ++d) kn[d] = kbase[(size_t)d * BT + gt];
            }
            // compute conv k into registers (not blocked by slot)
            double iv[14];
            #pragma unroll
            for (int c = 0; c < 14; ++c) {
                double acc = 0.0;
                #pragma unroll
                for (int kk = 0; kk < 13; ++kk) {
                    int d = kk < 6 ? 6 - kk : kk - 6;
                    acc = fma((double)xc[c + kk], kc[d], acc);
                }
                double xvv = (double)xc[c + 6];
                double dd  = xvv - acc;
                iv[c] = xvv - (dd > 0.0 ? dd : 0.0);
            }
            // wait slot free, write, release
            const int s = k & (RD - 1);
            while (__hip_atomic_load(&fl[CF(s)], __ATOMIC_ACQUIRE,
                                     __HIP_MEMORY_SCOPE_WORKGROUP) < k + 1 - RD)
                __builtin_amdgcn_s_sleep(1);
            #pragma unroll
            for (int c = 0; c < 14; ++c) Is[s][lane][cb + c] = iv[c];
            if (lane == 0)
                __hip_atomic_store(&fl[PF(h, s)], k + 1, __ATOMIC_RELEASE,
                                   __HIP_MEMORY_SCOPE_WORKGROUP);
            // rotate
            if (k + 1 < NT) {
                #pragma unroll
                for (int i = 0; i < 26; ++i) xc[i] = xn[i];
                #pragma unroll
                for (int d = 0; d < 7; ++d) kc[d] = kn[d];
            }
        }
    } else if (wid == 0) {
        // ========================== scan wave ===========================
        const int c    = lane;
        const int cidx = (c < CG) ? c : 0;
        double mem = 0.0;
        bool   r   = false;

        #pragma unroll 1
        for (int k = 0; k < NT; ++k) {
            const int s = k & (RD - 1);
            while (__hip_atomic_load(&fl[PF(0, s)], __ATOMIC_ACQUIRE,
                                     __HIP_MEMORY_SCOPE_WORKGROUP) < k + 1 ||
                   __hip_atomic_load(&fl[PF(1, s)], __ATOMIC_ACQUIRE,
                                     __HIP_MEMORY_SCOPE_WORKGROUP) < k + 1)
                __builtin_amdgcn_s_sleep(1);

            unsigned long long bits = 0ull;
            {
                double va[8], vam[8], vb[8], vbm[8];
                #pragma unroll
                for (int j = 0; j < 8; ++j) {
                    va[j] = Is[s][j][cidx]; vam[j] = va[j] - 1.0;
                }
                #pragma unroll
                for (int g = 0; g < 64; g += 16) {
                    #pragma unroll
                    for (int j = 0; j < 8; ++j) {
                        vb[j] = Is[s][g + 8 + j][cidx]; vbm[j] = vb[j] - 1.0;
                    }
                    #pragma unroll
                    for (int j = 0; j < 8; ++j) {
                        double m1 = fma(0.95, mem, va[j]);
                        double m2 = fma(0.95, mem, vam[j]);
                        mem = r ? m2 : m1;
                        r = mem > 1.0;
                        bits |= (unsigned long long)(r ? 1 : 0) << (g + j);
                    }
                    if (g + 16 < 64) {
                        #pragma unroll
                        for (int j = 0; j < 8; ++j) {
                            va[j] = Is[s][g + 16 + j][cidx]; vam[j] = va[j] - 1.0;
                        }
                    }
                    #pragma unroll
                    for (int j = 0; j < 8; ++j) {
                        double m1 = fma(0.95, mem, vb[j]);
                        double m2 = fma(0.95, mem, vbm[j]);
                        mem = r ? m2 : m1;
                        r = mem > 1.0;
                        bits |= (unsigned long long)(r ? 1 : 0) << (g + 8 + j);
                    }
                }
            }
            if (lane == 0)
                __hip_atomic_store(&fl[CF(s)], k + 1, __ATOMIC_RELEASE,
                                   __HIP_MEMORY_SCOPE_WORKGROUP);

            while (__hip_atomic_load(&fl[OW(s)], __ATOMIC_ACQUIRE,
                                     __HIP_MEMORY_SCOPE_WORKGROUP) < k + 1 - RD)
                __builtin_amdgcn_s_sleep(1);
            if (c < CG) bitsb[s][c] = bits;
            if (lane == 0)
                __hip_atomic_store(&fl[SF(s)], k + 1, __ATOMIC_RELEASE,
                                   __HIP_MEMORY_SCOPE_WORKGROUP);
        }
    } else {
        // ======================== out-writer wave ========================
        const int qq = lane & 15;            // float4 index within 64 t
        #pragma unroll 1
        for (int k = 0; k < NT; ++k) {
            const int s = k & (RD - 1);
            while (__hip_atomic_load(&fl[SF(s)], __ATOMIC_ACQUIRE,
                                     __HIP_MEMORY_SCOPE_WORKGROUP) < k + 1)
                __builtin_amdgcn_s_sleep(1);
            unsigned long long bb[7];
            #pragma unroll
            for (int i = 0; i < 7; ++i) {
                int cc = (lane >> 4) + 4 * i;          // 0..27
                bb[i] = bitsb[s][cc];
            }
            if (lane == 0)
                __hip_atomic_store(&fl[OW(s)], k + 1, __ATOMIC_RELEASE,
                                   __HIP_MEMORY_SCOPE_WORKGROUP);
            #pragma unroll
            for (int i = 0; i < 7; ++i) {
                int cc = (lane >> 4) + 4 * i;
                unsigned long long bv = bb[i] >> (4 * qq);
                float4 v;
                v.x = (bv & 1ull) ? 1.0f : 0.0f;
                v.y = (bv & 2ull) ? 1.0f : 0.0f;
                v.z = (bv & 4ull) ? 1.0f : 0.0f;
                v.w = (bv & 8ull) ? 1.0f : 0.0f;
                *(float4*)(obase + ((size_t)cc << 11) + k * TPB + 4 * qq) = v;
            }
        }
    }
}

// ---------------------------------------------------------------------------
extern "C" void kernel_launch(void* const* d_in, const int* in_sizes, int n_in,
                              void* d_out, int out_size, void* d_ws, size_t ws_size,
                              hipStream_t stream)
{
    const float* x  = (const float*)d_in[0];   // (32,1,224,2048) f32
    const float* lw = (const float*)d_in[1];   // (1,224) f32
    float* out = (float*)d_out;                // (32,1,224,2048) f32

    double* kernG = (double*)d_ws;             // SoA 7 * 65536 * 8 = 3,670,016 B

    kw<<<dim3(TTT / 64, BB), 256, 0, stream>>>(x, lw, kernG);
    kf<<<dim3(NCG, BB), 256, 0, stream>>>(x, kernG, out);
}